// Round 5
// baseline (8184.012 us; speedup 1.0000x reference)
//
#include <hip/hip_runtime.h>

// LSTM persistent-RNN kernel for MI355X (gfx950).
// B=64, T=512, D=1024, H=1024. out[t][b][h] fp32.
//
// Round 5: 64 blocks x 512 threads (16 units/block: 2 unit-subgroups x 4
// K-waves). Poll = pure spin (no s_sleep) on 16 flags/wave. Out-stores are
// plain cached (L2-ack, not HBM-ack at the next barrier drain). x/out
// addressing strength-reduced (pointer += stride per step).

typedef short short8 __attribute__((ext_vector_type(8)));
typedef float f32x4 __attribute__((ext_vector_type(4)));

#define NBLK 64
#define TPB 512

__device__ __forceinline__ unsigned bfbits(float f) {
  unsigned u = __float_as_uint(f);
  return ((u + 0x7fffu + ((u >> 16) & 1u)) >> 16) & 0xffffu;  // RNE
}

__device__ __forceinline__ short8 cvt8(const float* p) {
  const float4* q = (const float4*)p;
  float4 a = q[0], b = q[1];
  short8 r;
  r[0] = (short)bfbits(a.x); r[1] = (short)bfbits(a.y);
  r[2] = (short)bfbits(a.z); r[3] = (short)bfbits(a.w);
  r[4] = (short)bfbits(b.x); r[5] = (short)bfbits(b.y);
  r[6] = (short)bfbits(b.z); r[7] = (short)bfbits(b.w);
  return r;
}

__device__ __forceinline__ float sigmoidf_(float x) {
  return 1.0f / (1.0f + __expf(-x));
}
__device__ __forceinline__ float tanhf_(float x) {
  float ax = fabsf(x);
  float e = __expf(-2.0f * ax);  // in (0,1], never overflows
  float r = (1.0f - e) / (1.0f + e);
  return copysignf(r, x);
}

__global__ void cvt_x_kernel(const float* __restrict__ x,
                             unsigned short* __restrict__ xb, int n4) {
  int i = blockIdx.x * blockDim.x + threadIdx.x;
  int stride = gridDim.x * blockDim.x;
  const float4* xv = (const float4*)x;
  uint2* ov = (uint2*)xb;
  for (; i < n4; i += stride) {
    float4 v = xv[i];
    uint2 o;
    o.x = bfbits(v.x) | (bfbits(v.y) << 16);
    o.y = bfbits(v.z) | (bfbits(v.w) << 16);
    ov[i] = o;
  }
}

// Block bid owns hidden units [bid*16, bid*16+16), as two 8-unit subgroups
// G=0,1. Wave w (0..7): G = w>>2, kw = w&3 -> K-slice [256kw, 256kw+256) of
// both the x-half and h-half of K. Gate order 0=i,1=f,2=o,3=c.
// MFMA 16x16x32 bf16 layouts as verified in R1-R4 (guide m89/m91).
// hist: slot s holds h after step s-1; slot 0 = zeros. Step t reads slot t
// (gated by flags >= t+1), writes slot t+1, sets flag = t+2. Write-once
// addresses -> plain cached consumer loads can never be stale in-dispatch.
#define PART(G, kw, col, row) part[((((G)*4 + (kw)) * 32 + (col)) * 68) + (row)]

__global__ __launch_bounds__(TPB, 2) void lstm_persist(
    const float* __restrict__ x, const unsigned short* __restrict__ xb,
    const float* __restrict__ Wi, const float* __restrict__ Wf,
    const float* __restrict__ Wo, const float* __restrict__ Wc,
    const float* __restrict__ bi, const float* __restrict__ bfv,
    const float* __restrict__ bo, const float* __restrict__ bc,
    unsigned short* __restrict__ hist, unsigned* __restrict__ flags,
    float* __restrict__ out) {
  constexpr int B = 64, T = 512, D = 1024, H = 1024;
  const int tid = threadIdx.x;
  const int bid = blockIdx.x;
  const int lane = tid & 63;
  const int w = tid >> 6;        // wave 0..7
  const int G = w >> 2;          // unit subgroup 0/1
  const int kw = w & 3;          // K-wave -> slice [256kw, 256kw+256)
  const int cl = lane & 15;
  const int kg = lane >> 4;      // k-group within fragment
  const int j0 = bid * 16;

  __builtin_amdgcn_fence(__ATOMIC_ACQUIRE, "agent");

  extern __shared__ float part[];  // [2][4][32][68] fp32 partials (69632 B)

  // ---- Load weight fragments into registers (once) ----
  const float* Wg[4] = {Wi, Wf, Wo, Wc};
  short8 bxw[2][8], bhw[2][8];
#pragma unroll
  for (int nt = 0; nt < 2; ++nt) {
    int g = 2 * nt + (cl >> 3);
    const float* wrow = Wg[g] + (size_t)(j0 + 8 * G + (cl & 7)) * 2048;
#pragma unroll
    for (int kf = 0; kf < 8; ++kf) {
      int kx = 256 * kw + 32 * kf + 8 * kg;
      bxw[nt][kf] = cvt8(wrow + kx);         // x-part columns [0,1024)
      bhw[nt][kf] = cvt8(wrow + 1024 + kx);  // h-part columns [1024,2048)
    }
  }

  // ---- Activation assignment: thread -> (row, unit pair 2up,2up+1) ----
  const int row = tid >> 3;  // 0..63
  const int up = tid & 7;    // unit pair 0..7 (units j0+2up, j0+2up+1)
  float biasv[4][2];
#pragma unroll
  for (int k = 0; k < 2; ++k) {
    biasv[0][k] = bi[j0 + 2 * up + k];
    biasv[1][k] = bfv[j0 + 2 * up + k];
    biasv[2][k] = bo[j0 + 2 * up + k];
    biasv[3][k] = bc[j0 + 2 * up + k];
  }
  float cst[2] = {0.0f, 0.0f};

  const int kxbase = 256 * kw + 8 * kg;

  // Strength-reduced x pointers: one per mt, advance by D elements/step.
  const unsigned short* pxb[4];
#pragma unroll
  for (int mt = 0; mt < 4; ++mt)
    pxb[mt] = xb + (size_t)(16 * mt + cl) * T * D + kxbase;
  // h-load per-lane element offsets (constant): row (16mt+cl), k kxbase.
  int hoff[4];
#pragma unroll
  for (int mt = 0; mt < 4; ++mt) hoff[mt] = (16 * mt + cl) * H + kxbase;
  // Strength-reduced out pointer: advance by B*H floats/step.
  float* pout = out + (size_t)row * H + j0 + 2 * up;

  // ---- Zero hist slot 0 (coherent write-through), then arrive ----
  unsigned* hz = (unsigned*)hist;
  __hip_atomic_store(&hz[bid * TPB + tid], 0u, __ATOMIC_RELAXED,
                     __HIP_MEMORY_SCOPE_AGENT);
  __syncthreads();  // drains the coherent stores before flagging
  if (tid == 0)
    __hip_atomic_store(&flags[bid * 32], 1u, __ATOMIC_RELAXED,
                       __HIP_MEMORY_SCOPE_AGENT);

  for (int t = 0; t < T; ++t) {
    const unsigned short* hprev = hist + (size_t)t * 65536;
    unsigned short* hnext = hist + (size_t)(t + 1) * 65536;

    f32x4 acc[4][2];
#pragma unroll
    for (int mt = 0; mt < 4; ++mt)
#pragma unroll
      for (int nt = 0; nt < 2; ++nt) acc[mt][nt] = (f32x4)0.0f;

    // ---- x-part MFMAs (independent of h -> before the barrier wait) ----
#pragma unroll
    for (int kf = 0; kf < 8; ++kf) {
      short8 af[4];
#pragma unroll
      for (int mt = 0; mt < 4; ++mt)
        af[mt] = *(const short8*)(pxb[mt] + 32 * kf);
#pragma unroll
      for (int mt = 0; mt < 4; ++mt) {
        acc[mt][0] = __builtin_amdgcn_mfma_f32_16x16x32_bf16(
            af[mt], bxw[0][kf], acc[mt][0], 0, 0, 0);
        acc[mt][1] = __builtin_amdgcn_mfma_f32_16x16x32_bf16(
            af[mt], bxw[1][kf], acc[mt][1], 0, 0, 0);
      }
    }
#pragma unroll
    for (int mt = 0; mt < 4; ++mt) pxb[mt] += D;

    // ---- Wait: K-slice [256kw,256kw+256) produced by blocks
    // [16kw, 16kw+16). Pure spin poll (no s_sleep) on 16 flags. ----
    {
      const unsigned target = (unsigned)(t + 1);
      const unsigned* fp = flags + (size_t)(16 * kw + (lane & 15)) * 32;
      while (true) {
        unsigned v =
            __hip_atomic_load(fp, __ATOMIC_RELAXED, __HIP_MEMORY_SCOPE_AGENT);
        if (__all((int)(v >= target))) break;
      }
    }
    asm volatile("" ::: "memory");  // no h-loads hoisted above the poll

    // ---- h-part: plain cached loads (write-once -> stale-free) ----
    short8 ah[8][4];
#pragma unroll
    for (int kf = 0; kf < 8; ++kf) {
#pragma unroll
      for (int mt = 0; mt < 4; ++mt)
        ah[kf][mt] = *(const short8*)(hprev + hoff[mt] + 32 * kf);
    }
#pragma unroll
    for (int kf = 0; kf < 8; ++kf) {
#pragma unroll
      for (int mt = 0; mt < 4; ++mt) {
        acc[mt][0] = __builtin_amdgcn_mfma_f32_16x16x32_bf16(
            ah[kf][mt], bhw[0][kf], acc[mt][0], 0, 0, 0);
        acc[mt][1] = __builtin_amdgcn_mfma_f32_16x16x32_bf16(
            ah[kf][mt], bhw[1][kf], acc[mt][1], 0, 0, 0);
      }
    }

    // ---- Cross-wave reduce via LDS ----
#pragma unroll
    for (int mt = 0; mt < 4; ++mt)
#pragma unroll
      for (int nt = 0; nt < 2; ++nt)
        *(f32x4*)&PART(G, kw, 16 * nt + cl, 16 * mt + 4 * kg) = acc[mt][nt];
    __syncthreads();

    // ---- Activations + cell update ----
    float hv[2];
#pragma unroll
    for (int k = 0; k < 2; ++k) {
      int u = 2 * up + k;              // unit 0..15
      int uG = u >> 3;                 // subgroup
      int uc = u & 7;                  // unit within subgroup
      float pre[4];
#pragma unroll
      for (int g = 0; g < 4; ++g) {
        float s = biasv[g][k];
#pragma unroll
        for (int ww = 0; ww < 4; ++ww) s += PART(uG, ww, 8 * g + uc, row);
        pre[g] = s;
      }
      float iv = sigmoidf_(pre[0]);
      float fv = sigmoidf_(pre[1]);
      float ov = sigmoidf_(pre[2]);
      float gv = tanhf_(pre[3]);
      cst[k] = fv * cst[k] + iv * gv;
      hv[k] = ov * tanhf_(cst[k]);
    }
    // packed coherent h store (1 dword) -- the only store that must drain
    unsigned hpack = bfbits(hv[0]) | (bfbits(hv[1]) << 16);
    __hip_atomic_store((unsigned*)(hnext + (size_t)row * H + j0 + 2 * up),
                       hpack, __ATOMIC_RELAXED, __HIP_MEMORY_SCOPE_AGENT);

    // ---- Publish h_t: drain h stores, then arrive (plain flag store) ----
    __syncthreads();
    asm volatile("" ::: "memory");
    if (tid == 0)
      __hip_atomic_store(&flags[bid * 32], (unsigned)(t + 2), __ATOMIC_RELAXED,
                         __HIP_MEMORY_SCOPE_AGENT);

    // ---- out store AFTER arrive: plain cached (acks from L2 fast) ----
    pout[0] = hv[0];
    pout[1] = hv[1];
    pout += (size_t)B * H;
  }
}

extern "C" void kernel_launch(void* const* d_in, const int* in_sizes, int n_in,
                              void* d_out, int out_size, void* d_ws,
                              size_t ws_size, hipStream_t stream) {
  const float* x = (const float*)d_in[0];
  const float* Wi = (const float*)d_in[1];
  const float* bi = (const float*)d_in[2];
  const float* Wf = (const float*)d_in[3];
  const float* bfv = (const float*)d_in[4];
  const float* Wo = (const float*)d_in[5];
  const float* bo = (const float*)d_in[6];
  const float* Wc = (const float*)d_in[7];
  const float* bc = (const float*)d_in[8];
  float* out = (float*)d_out;

  char* ws = (char*)d_ws;
  const size_t xb_bytes = (size_t)64 * 512 * 1024 * 2;    // 64 MiB bf16 x
  const size_t hist_bytes = (size_t)513 * 64 * 1024 * 2;  // 64.1 MiB hist
  const size_t fl_bytes = (size_t)NBLK * 32 * 4;          // flag array

  unsigned short* xb = (unsigned short*)ws;
  size_t off = xb_bytes;
  unsigned short* hist = (unsigned short*)(ws + off);
  off += hist_bytes;
  unsigned* flags = (unsigned*)(ws + off);

  hipMemsetAsync(flags, 0, fl_bytes, stream);
  cvt_x_kernel<<<2048, 256, 0, stream>>>(x, xb, (64 * 512 * 1024) / 4);
  lstm_persist<<<NBLK, TPB, 69632, stream>>>(x, xb, Wi, Wf, Wo, Wc, bi, bfv,
                                             bo, bc, hist, flags, out);
}

// Round 7
// 5111.281 us; speedup vs baseline: 1.6012x; 1.6012x over previous
//
#include <hip/hip_runtime.h>

// LSTM persistent-RNN kernel for MI355X (gfx950).
// B=64, T=512, D=1024, H=1024. out[t][b][h] fp32.
//
// Round 6b: R4 base (128 blocks x 256 thr, hist buffer, per-wave 32-flag
// poll) + reworked publish path: activations stage h into LDS; wave 0 alone
// does 64 coalesced dwordx4 coherent stores + vmcnt(0) + flag store; waves
// 1-3 run ahead. Out-stores are plain cached. (R6 compile fix: asm store
// data must be an ext_vector type, not struct uint4.)

typedef short short8 __attribute__((ext_vector_type(8)));
typedef float f32x4 __attribute__((ext_vector_type(4)));
typedef unsigned u32x4 __attribute__((ext_vector_type(4)));

#define NBLK 128
#define TPB 256

__device__ __forceinline__ unsigned bfbits(float f) {
  unsigned u = __float_as_uint(f);
  return ((u + 0x7fffu + ((u >> 16) & 1u)) >> 16) & 0xffffu;  // RNE
}

__device__ __forceinline__ short8 cvt8(const float* p) {
  const float4* q = (const float4*)p;
  float4 a = q[0], b = q[1];
  short8 r;
  r[0] = (short)bfbits(a.x); r[1] = (short)bfbits(a.y);
  r[2] = (short)bfbits(a.z); r[3] = (short)bfbits(a.w);
  r[4] = (short)bfbits(b.x); r[5] = (short)bfbits(b.y);
  r[6] = (short)bfbits(b.z); r[7] = (short)bfbits(b.w);
  return r;
}

__device__ __forceinline__ float sigmoidf_(float x) {
  return 1.0f / (1.0f + __expf(-x));
}
__device__ __forceinline__ float tanhf_(float x) {
  float ax = fabsf(x);
  float e = __expf(-2.0f * ax);  // in (0,1], never overflows
  float r = (1.0f - e) / (1.0f + e);
  return copysignf(r, x);
}

__global__ void cvt_x_kernel(const float* __restrict__ x,
                             unsigned short* __restrict__ xb, int n4) {
  int i = blockIdx.x * blockDim.x + threadIdx.x;
  int stride = gridDim.x * blockDim.x;
  const float4* xv = (const float4*)x;
  uint2* ov = (uint2*)xb;
  for (; i < n4; i += stride) {
    float4 v = xv[i];
    uint2 o;
    o.x = bfbits(v.x) | (bfbits(v.y) << 16);
    o.y = bfbits(v.z) | (bfbits(v.w) << 16);
    ov[i] = o;
  }
}

// Gate order: 0=i, 1=f, 2=o, 3=c(g). Block bid owns hidden units
// [bid*8, bid*8+8). Its 32 gate-columns: col c = 8*g + u.
// MFMA 16x16x32 bf16. A-frag: lane l -> row l&15, k = 8*(l>>4)+j.
// B-frag: lane l -> col l&15, k = 8*(l>>4)+j. C/D: col=l&15,
// row=(l>>4)*4+reg (HW-verified per guide m89/m91).
//
// hist layout: slot s holds h after step s-1; slot 0 = zeros. Step t reads
// slot t (gated by flags >= t+1), writes slot t+1, then sets flag = t+2.
// Write-once addresses -> plain cached consumer loads can never be stale.
__global__ __launch_bounds__(TPB, 1) void lstm_persist(
    const float* __restrict__ x, const unsigned short* __restrict__ xb,
    const float* __restrict__ Wi, const float* __restrict__ Wf,
    const float* __restrict__ Wo, const float* __restrict__ Wc,
    const float* __restrict__ bi, const float* __restrict__ bfv,
    const float* __restrict__ bo, const float* __restrict__ bc,
    unsigned short* __restrict__ hist, unsigned* __restrict__ flags,
    float* __restrict__ out) {
  constexpr int B = 64, T = 512, D = 1024, H = 1024;
  const int tid = threadIdx.x;
  const int bid = blockIdx.x;
  const int lane = tid & 63;
  const int w = tid >> 6;    // wave 0..3 -> K-slice [256w, 256w+256)
  const int cl = lane & 15;
  const int kg = lane >> 4;  // k-group within fragment
  const int j0 = bid * 8;

  __builtin_amdgcn_fence(__ATOMIC_ACQUIRE, "agent");

  __shared__ float part[4][32][68];  // [wave][col][row+pad] fp32 partials
  __shared__ unsigned hstage[256];   // packed bf16x2, hstage[tid] layout ==
                                     // row-major [64 rows][4 dwords]

  // ---- Load weight fragments into registers (once) ----
  const float* Wg[4] = {Wi, Wf, Wo, Wc};
  short8 bxw[2][8], bhw[2][8];
#pragma unroll
  for (int nt = 0; nt < 2; ++nt) {
    int g = 2 * nt + (cl >> 3);
    const float* wrow = Wg[g] + (size_t)(j0 + (cl & 7)) * 2048;
#pragma unroll
    for (int kf = 0; kf < 8; ++kf) {
      int kx = 256 * w + 32 * kf + 8 * kg;
      bxw[nt][kf] = cvt8(wrow + kx);         // x-part columns [0,1024)
      bhw[nt][kf] = cvt8(wrow + 1024 + kx);  // h-part columns [1024,2048)
    }
  }

  // ---- Activation-stage assignment: thread -> (row, unit-pair) ----
  const int row = tid >> 2;  // batch row 0..63
  const int up = tid & 3;    // unit pair: units 2*up, 2*up+1
  float biasv[4][2];
#pragma unroll
  for (int k = 0; k < 2; ++k) {
    biasv[0][k] = bi[j0 + 2 * up + k];
    biasv[1][k] = bfv[j0 + 2 * up + k];
    biasv[2][k] = bo[j0 + 2 * up + k];
    biasv[3][k] = bc[j0 + 2 * up + k];
  }
  float cst[2] = {0.0f, 0.0f};  // cell state (registers, persistent)

  const int kxbase = 256 * w + 8 * kg;

  // ---- Zero hist slot 0 (coherent write-through), then arrive ----
  unsigned* hz = (unsigned*)hist;
  __hip_atomic_store(&hz[bid * TPB + tid], 0u, __ATOMIC_RELAXED,
                     __HIP_MEMORY_SCOPE_AGENT);
  __syncthreads();  // drains the coherent stores before flagging
  if (tid == 0)
    __hip_atomic_store(&flags[bid * 32], 1u, __ATOMIC_RELAXED,
                       __HIP_MEMORY_SCOPE_AGENT);

  for (int t = 0; t < T; ++t) {
    const unsigned short* hprev = hist + (size_t)t * 65536;
    unsigned short* hnext = hist + (size_t)(t + 1) * 65536;

    f32x4 acc[4][2];
#pragma unroll
    for (int mt = 0; mt < 4; ++mt)
#pragma unroll
      for (int nt = 0; nt < 2; ++nt) acc[mt][nt] = (f32x4)0.0f;

    // ---- x-part MFMAs (independent of h -> before the barrier wait) ----
#pragma unroll
    for (int kf = 0; kf < 8; ++kf) {
      int kx = kxbase + 32 * kf;
      short8 af[4];
#pragma unroll
      for (int mt = 0; mt < 4; ++mt) {
        int b = 16 * mt + cl;
        af[mt] = *(const short8*)(xb + ((size_t)b * T + t) * D + kx);
      }
#pragma unroll
      for (int mt = 0; mt < 4; ++mt) {
        acc[mt][0] = __builtin_amdgcn_mfma_f32_16x16x32_bf16(
            af[mt], bxw[0][kf], acc[mt][0], 0, 0, 0);
        acc[mt][1] = __builtin_amdgcn_mfma_f32_16x16x32_bf16(
            af[mt], bxw[1][kf], acc[mt][1], 0, 0, 0);
      }
    }

    // ---- Per-wave partial barrier: wave w's K-slice [256w, 256w+256) is
    // produced exactly by blocks [32w, 32w+32). Poll only those 32 flags.
    {
      const unsigned target = (unsigned)(t + 1);
      const unsigned* fp = flags + (size_t)(32 * w + (lane & 31)) * 32;
      while (true) {
        unsigned v =
            __hip_atomic_load(fp, __ATOMIC_RELAXED, __HIP_MEMORY_SCOPE_AGENT);
        if (__all((int)(v >= target))) break;
        __builtin_amdgcn_s_sleep(1);
      }
    }
    asm volatile("" ::: "memory");  // no h-loads hoisted above the poll

    // ---- h-part: plain cached loads (write-once -> stale-free) ----
    short8 ah[8][4];
#pragma unroll
    for (int kf = 0; kf < 8; ++kf) {
      int kh = kxbase + 32 * kf;
#pragma unroll
      for (int mt = 0; mt < 4; ++mt)
        ah[kf][mt] = *(const short8*)(hprev + (size_t)(16 * mt + cl) * H + kh);
    }
#pragma unroll
    for (int kf = 0; kf < 8; ++kf) {
#pragma unroll
      for (int mt = 0; mt < 4; ++mt) {
        acc[mt][0] = __builtin_amdgcn_mfma_f32_16x16x32_bf16(
            ah[kf][mt], bhw[0][kf], acc[mt][0], 0, 0, 0);
        acc[mt][1] = __builtin_amdgcn_mfma_f32_16x16x32_bf16(
            ah[kf][mt], bhw[1][kf], acc[mt][1], 0, 0, 0);
      }
    }

    // ---- Cross-wave reduce via LDS ----
#pragma unroll
    for (int mt = 0; mt < 4; ++mt)
#pragma unroll
      for (int nt = 0; nt < 2; ++nt)
        *(f32x4*)&part[w][16 * nt + cl][16 * mt + 4 * kg] = acc[mt][nt];
    __syncthreads();

    // ---- Activations + cell update: thread -> (row, units 2up..2up+1) ----
    float hv[2];
#pragma unroll
    for (int k = 0; k < 2; ++k) {
      int u = 2 * up + k;
      float pre[4];
#pragma unroll
      for (int g = 0; g < 4; ++g) {
        float s = biasv[g][k];
#pragma unroll
        for (int ww = 0; ww < 4; ++ww) s += part[ww][8 * g + u][row];
        pre[g] = s;
      }
      float iv = sigmoidf_(pre[0]);
      float fv = sigmoidf_(pre[1]);
      float ov = sigmoidf_(pre[2]);
      float gv = tanhf_(pre[3]);
      cst[k] = fv * cst[k] + iv * gv;
      hv[k] = ov * tanhf_(cst[k]);
    }
    // Stage packed h in LDS: hstage[tid] == [row][dword up] row-major.
    hstage[tid] = bfbits(hv[0]) | (bfbits(hv[1]) << 16);
    __syncthreads();

    // ---- Publish (wave 0 only): 64 coalesced coherent dwordx4 stores,
    // drain exactly those, then flag. Waves 1-3 run ahead into t+1. ----
    if (w == 0) {
      u32x4 h4 = *(const u32x4*)&hstage[4 * lane];  // row `lane`, 8 units
      unsigned short* dst = hnext + (size_t)lane * H + j0;
      asm volatile("global_store_dwordx4 %0, %1, off sc0 sc1" ::"v"(dst),
                   "v"(h4)
                   : "memory");
      asm volatile("s_waitcnt vmcnt(0)" ::: "memory");
      if (lane == 0)
        __hip_atomic_store(&flags[bid * 32], (unsigned)(t + 2),
                           __ATOMIC_RELAXED, __HIP_MEMORY_SCOPE_AGENT);
    }

    // ---- out store (plain cached; acks from L2, off the publish path) ----
    float* op = out + ((size_t)t * B + row) * H + j0 + 2 * up;
    *(float2*)op = make_float2(hv[0], hv[1]);
  }
}

extern "C" void kernel_launch(void* const* d_in, const int* in_sizes, int n_in,
                              void* d_out, int out_size, void* d_ws,
                              size_t ws_size, hipStream_t stream) {
  const float* x = (const float*)d_in[0];
  const float* Wi = (const float*)d_in[1];
  const float* bi = (const float*)d_in[2];
  const float* Wf = (const float*)d_in[3];
  const float* bfv = (const float*)d_in[4];
  const float* Wo = (const float*)d_in[5];
  const float* bo = (const float*)d_in[6];
  const float* Wc = (const float*)d_in[7];
  const float* bc = (const float*)d_in[8];
  float* out = (float*)d_out;

  char* ws = (char*)d_ws;
  const size_t xb_bytes = (size_t)64 * 512 * 1024 * 2;    // 64 MiB bf16 x
  const size_t hist_bytes = (size_t)513 * 64 * 1024 * 2;  // 64.1 MiB hist
  const size_t fl_bytes = (size_t)NBLK * 32 * 4;          // flag array

  unsigned short* xb = (unsigned short*)ws;
  size_t off = xb_bytes;
  unsigned short* hist = (unsigned short*)(ws + off);
  off += hist_bytes;
  unsigned* flags = (unsigned*)(ws + off);

  (void)hipMemsetAsync(flags, 0, fl_bytes, stream);
  cvt_x_kernel<<<2048, 256, 0, stream>>>(x, xb, (64 * 512 * 1024) / 4);
  lstm_persist<<<NBLK, TPB, 0, stream>>>(x, xb, Wi, Wf, Wo, Wc, bi, bfv, bo,
                                         bc, hist, flags, out);
}

// Round 8
// 4910.491 us; speedup vs baseline: 1.6666x; 1.0409x over previous
//
#include <hip/hip_runtime.h>

// LSTM persistent-RNN kernel for MI355X (gfx950).
// B=64, T=512, D=1024, H=1024. out[t][b][h] fp32.
//
// Round 7: R4 base + block-contiguous h layout. hist slot = [128 blocks] x
// [64 rows] x [8 units] bf16 (1024 B contiguous chunk per block = 8 full
// 128B lines). Producer stores are fully coalesced full-line writes (no
// partial-line write-through RMW); each consumer line depends on exactly one
// producer block (no 8-way cross-XCD line assembly).

typedef short short8 __attribute__((ext_vector_type(8)));
typedef float f32x4 __attribute__((ext_vector_type(4)));

#define NBLK 128
#define TPB 256

__device__ __forceinline__ unsigned bfbits(float f) {
  unsigned u = __float_as_uint(f);
  return ((u + 0x7fffu + ((u >> 16) & 1u)) >> 16) & 0xffffu;  // RNE
}

__device__ __forceinline__ short8 cvt8(const float* p) {
  const float4* q = (const float4*)p;
  float4 a = q[0], b = q[1];
  short8 r;
  r[0] = (short)bfbits(a.x); r[1] = (short)bfbits(a.y);
  r[2] = (short)bfbits(a.z); r[3] = (short)bfbits(a.w);
  r[4] = (short)bfbits(b.x); r[5] = (short)bfbits(b.y);
  r[6] = (short)bfbits(b.z); r[7] = (short)bfbits(b.w);
  return r;
}

__device__ __forceinline__ float sigmoidf_(float x) {
  return 1.0f / (1.0f + __expf(-x));
}
__device__ __forceinline__ float tanhf_(float x) {
  float ax = fabsf(x);
  float e = __expf(-2.0f * ax);  // in (0,1], never overflows
  float r = (1.0f - e) / (1.0f + e);
  return copysignf(r, x);
}

__global__ void cvt_x_kernel(const float* __restrict__ x,
                             unsigned short* __restrict__ xb, int n4) {
  int i = blockIdx.x * blockDim.x + threadIdx.x;
  int stride = gridDim.x * blockDim.x;
  const float4* xv = (const float4*)x;
  uint2* ov = (uint2*)xb;
  for (; i < n4; i += stride) {
    float4 v = xv[i];
    uint2 o;
    o.x = bfbits(v.x) | (bfbits(v.y) << 16);
    o.y = bfbits(v.z) | (bfbits(v.w) << 16);
    ov[i] = o;
  }
}

// Gate order: 0=i, 1=f, 2=o, 3=c(g). Block bid owns hidden units
// [bid*8, bid*8+8). Its 32 gate-columns: col c = 8*g + u.
// MFMA 16x16x32 bf16. A-frag: lane l -> row l&15, k = 8*(l>>4)+j.
// B-frag: lane l -> col l&15, k = 8*(l>>4)+j. C/D: col=l&15,
// row=(l>>4)*4+reg (HW-verified per guide m89/m91).
//
// hist layout (block-contiguous): slot s = [128 chunks][64 rows][8 units]
// bf16; chunk b' holds units [8b', 8b'+8). Unit u, row r lives at ushort
// offset u*64 + r*8 + (u&7)... i.e. chunk (u>>3)*512 + r*8 + (u&7).
// Slot s holds h after step s-1; slot 0 = zeros. Step t reads slot t (gated
// by flags >= t+1), writes slot t+1, then sets flag = t+2. Write-once
// addresses -> plain cached consumer loads can never be stale.
__global__ __launch_bounds__(TPB, 1) void lstm_persist(
    const float* __restrict__ x, const unsigned short* __restrict__ xb,
    const float* __restrict__ Wi, const float* __restrict__ Wf,
    const float* __restrict__ Wo, const float* __restrict__ Wc,
    const float* __restrict__ bi, const float* __restrict__ bfv,
    const float* __restrict__ bo, const float* __restrict__ bc,
    unsigned short* __restrict__ hist, unsigned* __restrict__ flags,
    float* __restrict__ out) {
  constexpr int B = 64, T = 512, D = 1024, H = 1024;
  const int tid = threadIdx.x;
  const int bid = blockIdx.x;
  const int lane = tid & 63;
  const int w = tid >> 6;    // wave 0..3 -> K-slice [256w, 256w+256)
  const int cl = lane & 15;
  const int kg = lane >> 4;  // k-group within fragment
  const int j0 = bid * 8;

  __builtin_amdgcn_fence(__ATOMIC_ACQUIRE, "agent");

  __shared__ float part[4][32][68];  // [wave][col][row+pad] fp32 partials

  // ---- Load weight fragments into registers (once) ----
  const float* Wg[4] = {Wi, Wf, Wo, Wc};
  short8 bxw[2][8], bhw[2][8];
#pragma unroll
  for (int nt = 0; nt < 2; ++nt) {
    int g = 2 * nt + (cl >> 3);
    const float* wrow = Wg[g] + (size_t)(j0 + (cl & 7)) * 2048;
#pragma unroll
    for (int kf = 0; kf < 8; ++kf) {
      int kx = 256 * w + 32 * kf + 8 * kg;
      bxw[nt][kf] = cvt8(wrow + kx);         // x-part columns [0,1024)
      bhw[nt][kf] = cvt8(wrow + 1024 + kx);  // h-part columns [1024,2048)
    }
  }

  // ---- Activation-stage assignment: thread -> (row, unit-pair) ----
  const int row = tid >> 2;  // batch row 0..63
  const int up = tid & 3;    // unit pair: units 2*up, 2*up+1
  float biasv[4][2];
#pragma unroll
  for (int k = 0; k < 2; ++k) {
    biasv[0][k] = bi[j0 + 2 * up + k];
    biasv[1][k] = bfv[j0 + 2 * up + k];
    biasv[2][k] = bo[j0 + 2 * up + k];
    biasv[3][k] = bc[j0 + 2 * up + k];
  }
  float cst[2] = {0.0f, 0.0f};  // cell state (registers, persistent)

  const int kxbase = 256 * w + 8 * kg;

  // ---- Zero hist slot 0 (coherent write-through, coalesced), arrive ----
  unsigned* hz = (unsigned*)hist;
  __hip_atomic_store(&hz[bid * TPB + tid], 0u, __ATOMIC_RELAXED,
                     __HIP_MEMORY_SCOPE_AGENT);
  __syncthreads();  // drains the coherent stores before flagging
  if (tid == 0)
    __hip_atomic_store(&flags[bid * 32], 1u, __ATOMIC_RELAXED,
                       __HIP_MEMORY_SCOPE_AGENT);

  for (int t = 0; t < T; ++t) {
    const unsigned short* hprev = hist + (size_t)t * 65536;
    unsigned short* hnext = hist + (size_t)(t + 1) * 65536;

    f32x4 acc[4][2];
#pragma unroll
    for (int mt = 0; mt < 4; ++mt)
#pragma unroll
      for (int nt = 0; nt < 2; ++nt) acc[mt][nt] = (f32x4)0.0f;

    // ---- x-part MFMAs (independent of h -> before the barrier wait) ----
#pragma unroll
    for (int kf = 0; kf < 8; ++kf) {
      int kx = kxbase + 32 * kf;
      short8 af[4];
#pragma unroll
      for (int mt = 0; mt < 4; ++mt) {
        int b = 16 * mt + cl;
        af[mt] = *(const short8*)(xb + ((size_t)b * T + t) * D + kx);
      }
#pragma unroll
      for (int mt = 0; mt < 4; ++mt) {
        acc[mt][0] = __builtin_amdgcn_mfma_f32_16x16x32_bf16(
            af[mt], bxw[0][kf], acc[mt][0], 0, 0, 0);
        acc[mt][1] = __builtin_amdgcn_mfma_f32_16x16x32_bf16(
            af[mt], bxw[1][kf], acc[mt][1], 0, 0, 0);
      }
    }

    // ---- Per-wave partial barrier: wave w's K-slice [256w, 256w+256) is
    // produced exactly by blocks [32w, 32w+32). Poll only those 32 flags.
    {
      const unsigned target = (unsigned)(t + 1);
      const unsigned* fp = flags + (size_t)(32 * w + (lane & 31)) * 32;
      while (true) {
        unsigned v =
            __hip_atomic_load(fp, __ATOMIC_RELAXED, __HIP_MEMORY_SCOPE_AGENT);
        if (__all((int)(v >= target))) break;
        __builtin_amdgcn_s_sleep(1);
      }
    }
    asm volatile("" ::: "memory");  // no h-loads hoisted above the poll

    // ---- h-part: plain cached loads, block-contiguous layout.
    // Fragment (kf,mt): units u0..u0+7 (u0 = kxbase+32kf, u0%8==0), row
    // 16mt+cl -> single 16B load at ushort offset u0*64 + row*8. ----
    short8 ah[8][4];
#pragma unroll
    for (int kf = 0; kf < 8; ++kf) {
      int u0 = kxbase + 32 * kf;
#pragma unroll
      for (int mt = 0; mt < 4; ++mt)
        ah[kf][mt] =
            *(const short8*)(hprev + (size_t)u0 * 64 + (16 * mt + cl) * 8);
    }
#pragma unroll
    for (int kf = 0; kf < 8; ++kf) {
#pragma unroll
      for (int mt = 0; mt < 4; ++mt) {
        acc[mt][0] = __builtin_amdgcn_mfma_f32_16x16x32_bf16(
            ah[kf][mt], bhw[0][kf], acc[mt][0], 0, 0, 0);
        acc[mt][1] = __builtin_amdgcn_mfma_f32_16x16x32_bf16(
            ah[kf][mt], bhw[1][kf], acc[mt][1], 0, 0, 0);
      }
    }

    // ---- Cross-wave reduce via LDS ----
#pragma unroll
    for (int mt = 0; mt < 4; ++mt)
#pragma unroll
      for (int nt = 0; nt < 2; ++nt)
        *(f32x4*)&part[w][16 * nt + cl][16 * mt + 4 * kg] = acc[mt][nt];
    __syncthreads();

    // ---- Activations + cell update: thread -> (row, units 2up..2up+1) ----
    float hv[2];
#pragma unroll
    for (int k = 0; k < 2; ++k) {
      int u = 2 * up + k;
      float pre[4];
#pragma unroll
      for (int g = 0; g < 4; ++g) {
        float s = biasv[g][k];
#pragma unroll
        for (int ww = 0; ww < 4; ++ww) s += part[ww][8 * g + u][row];
        pre[g] = s;
      }
      float iv = sigmoidf_(pre[0]);
      float fv = sigmoidf_(pre[1]);
      float ov = sigmoidf_(pre[2]);
      float gv = tanhf_(pre[3]);
      cst[k] = fv * cst[k] + iv * gv;
      hv[k] = ov * tanhf_(cst[k]);
    }
    // Packed coherent h store: block-contiguous chunk, dword index == tid
    // (chunk dword = row*4 + up = tid). Fully coalesced, 8 full lines/block.
    unsigned hpack = bfbits(hv[0]) | (bfbits(hv[1]) << 16);
    __hip_atomic_store((unsigned*)hnext + bid * 256 + tid, hpack,
                       __ATOMIC_RELAXED, __HIP_MEMORY_SCOPE_AGENT);

    // ---- Publish h_t: drain h stores, then arrive (plain flag store) ----
    __syncthreads();
    asm volatile("" ::: "memory");
    if (tid == 0)
      __hip_atomic_store(&flags[bid * 32], (unsigned)(t + 2), __ATOMIC_RELAXED,
                         __HIP_MEMORY_SCOPE_AGENT);

    // ---- out store AFTER arrive: drains during next step's poll ----
    float* op = out + ((size_t)t * B + row) * H + j0 + 2 * up;
    __builtin_nontemporal_store(hv[0], op);
    __builtin_nontemporal_store(hv[1], op + 1);
  }
}

extern "C" void kernel_launch(void* const* d_in, const int* in_sizes, int n_in,
                              void* d_out, int out_size, void* d_ws,
                              size_t ws_size, hipStream_t stream) {
  const float* x = (const float*)d_in[0];
  const float* Wi = (const float*)d_in[1];
  const float* bi = (const float*)d_in[2];
  const float* Wf = (const float*)d_in[3];
  const float* bfv = (const float*)d_in[4];
  const float* Wo = (const float*)d_in[5];
  const float* bo = (const float*)d_in[6];
  const float* Wc = (const float*)d_in[7];
  const float* bc = (const float*)d_in[8];
  float* out = (float*)d_out;

  char* ws = (char*)d_ws;
  const size_t xb_bytes = (size_t)64 * 512 * 1024 * 2;    // 64 MiB bf16 x
  const size_t hist_bytes = (size_t)513 * 64 * 1024 * 2;  // 64.1 MiB hist
  const size_t fl_bytes = (size_t)NBLK * 32 * 4;          // flag array

  unsigned short* xb = (unsigned short*)ws;
  size_t off = xb_bytes;
  unsigned short* hist = (unsigned short*)(ws + off);
  off += hist_bytes;
  unsigned* flags = (unsigned*)(ws + off);

  (void)hipMemsetAsync(flags, 0, fl_bytes, stream);
  cvt_x_kernel<<<2048, 256, 0, stream>>>(x, xb, (64 * 512 * 1024) / 4);
  lstm_persist<<<NBLK, TPB, 0, stream>>>(x, xb, Wi, Wf, Wo, Wc, bi, bfv, bo,
                                         bc, hist, flags, out);
}